// Round 2
// baseline (264.301 us; speedup 1.0000x reference)
//
#include <hip/hip_runtime.h>
#include <hip/hip_bf16.h>
#include <stdint.h>

typedef __bf16 bf16x8 __attribute__((ext_vector_type(8)));
typedef float f32x4 __attribute__((ext_vector_type(4)));

#define MAXD 40
#define ND   81
#define CSZ  256
#define HSZ  128
#define WSZ  416
#define HW   (HSZ * WSZ)
#define WT   208          // w-tile per block
#define RROWS 288         // 208 + 2*40 halo rows of R
#define RST  20           // u32 per LDS row (32 bf16 data + 8 bf16 pad)
#define KC   32
#define NCHUNK 8

static __device__ __forceinline__ uint32_t pk2(float a, float b) {
    union { __bf16 h[2]; uint32_t u; } v;
    v.h[0] = (__bf16)a; v.h[1] = (__bf16)b;
    return v.u;
}

__global__ __launch_bounds__(256, 4)
void corr_mfma_kernel(const float* __restrict__ left,
                      const float* __restrict__ right,
                      float* __restrict__ out) {
    __shared__ uint32_t Lt[WT * RST];     // [w][cpair] packed bf16x2 : 16640 B
    __shared__ uint32_t Rt[RROWS * RST];  // [u][cpair]               : 23040 B

    const int t    = threadIdx.x;
    const int bid  = blockIdx.x;
    const int wt   = bid & 1;
    const int bh   = bid >> 1;
    const int b    = bh >> 7;
    const int h    = bh & 127;
    const int w0   = wt * WT;

    const int l15  = t & 15;
    const int l4   = (t >> 4) & 3;
    const int wave = t >> 6;

    const int cpair = 4 * wave + l4;   // 0..15
    const int cs    = 2 * cpair;       // even channel offset within chunk

    f32x4 acc[3][6];
    f32x4 accx[2];
    #pragma unroll
    for (int ri = 0; ri < 3; ++ri)
        #pragma unroll
        for (int j = 0; j < 6; ++j)
            acc[ri][j] = (f32x4)0.0f;
    accx[0] = (f32x4)0.0f;
    accx[1] = (f32x4)0.0f;

    const size_t slab = ((size_t)b * CSZ) * HW + (size_t)h * WSZ;
    const float* Lp = left  + slab + w0 + l15;
    const float* Rp = right + slab;
    const int ub = w0 - MAXD + l15;

    uint32_t* Lw = &Lt[l15 * RST + cpair];
    uint32_t* Rw = &Rt[l15 * RST + cpair];

    for (int ck = 0; ck < NCHUNK; ++ck) {
        const size_t coff = (size_t)(ck * KC + cs) * HW;
        const float* Lc = Lp + coff;
        const float* Rc = Rp + coff;

        // ---- stage L: 13 x (2 loads -> 1 packed b32 write, conflict-free banks) ----
        #pragma unroll
        for (int i = 0; i < 13; ++i) {
            float a0 = Lc[16 * i];
            float a1 = Lc[16 * i + HW];
            Lw[320 * i] = pk2(a0, a1);
        }
        // ---- stage R (with halo, predicated-zero outside image) ----
        #pragma unroll
        for (int i = 0; i < 18; ++i) {
            const int u = ub + 16 * i;
            const bool ok = (unsigned)u < (unsigned)WSZ;
            float r0 = ok ? Rc[u]      : 0.0f;
            float r1 = ok ? Rc[u + HW] : 0.0f;
            Rw[320 * i] = pk2(r0, r1);
        }
        __syncthreads();

        const __bf16* Lb = (const __bf16*)Lt;
        const __bf16* Rb = (const __bf16*)Rt;
        // rows 0..11: 3 per wave
        #pragma unroll
        for (int ri = 0; ri < 3; ++ri) {
            const int row = wave + 4 * ri;
            const bf16x8 a = *(const bf16x8*)(Lb + (16 * row + l15) * 40 + 8 * l4);
            #pragma unroll
            for (int j = 0; j < 6; ++j) {
                const bf16x8 bb = *(const bf16x8*)(Rb + (16 * (row + j) + l15) * 40 + 8 * l4);
                acc[ri][j] = __builtin_amdgcn_mfma_f32_16x16x32_bf16(a, bb, acc[ri][j], 0, 0, 0);
            }
        }
        // row 12: u-tiles split across waves (wave0:{0,4} wave1:{1,5} wave2:{2} wave3:{3})
        {
            const bf16x8 a12 = *(const bf16x8*)(Lb + (16 * 12 + l15) * 40 + 8 * l4);
            #pragma unroll
            for (int q = 0; q < 2; ++q) {
                if (q == 0 || wave < 2) {
                    const int jx = wave + 4 * q;
                    const bf16x8 bb = *(const bf16x8*)(Rb + (16 * (12 + jx) + l15) * 40 + 8 * l4);
                    accx[q] = __builtin_amdgcn_mfma_f32_16x16x32_bf16(a12, bb, accx[q], 0, 0, 0);
                }
            }
        }
        __syncthreads();
    }

    // ---- epilogue: C row m = 4*l4 + r (w offset), col n = l15 (u offset); d = 16j + n - m ----
    const float scale = 1.0f / 256.0f;
    #pragma unroll
    for (int ri = 0; ri < 3; ++ri) {
        const int row = wave + 4 * ri;
        const int wbase = w0 + 16 * row;
        #pragma unroll
        for (int j = 0; j < 6; ++j) {
            #pragma unroll
            for (int r = 0; r < 4; ++r) {
                const int m = 4 * l4 + r;
                const int d = 16 * j + l15 - m;
                if ((unsigned)d < (unsigned)ND) {
                    out[(((size_t)b * ND + d) * HSZ + h) * WSZ + (wbase + m)] = acc[ri][j][r] * scale;
                }
            }
        }
    }
    #pragma unroll
    for (int q = 0; q < 2; ++q) {
        if (q == 0 || wave < 2) {
            const int jx = wave + 4 * q;
            #pragma unroll
            for (int r = 0; r < 4; ++r) {
                const int m = 4 * l4 + r;
                const int d = 16 * jx + l15 - m;
                if ((unsigned)d < (unsigned)ND) {
                    out[(((size_t)b * ND + d) * HSZ + h) * WSZ + (w0 + 192 + m)] = accx[q][r] * scale;
                }
            }
        }
    }
}

extern "C" void kernel_launch(void* const* d_in, const int* in_sizes, int n_in,
                              void* d_out, int out_size, void* d_ws, size_t ws_size,
                              hipStream_t stream) {
    const float* left  = (const float*)d_in[0];
    const float* right = (const float*)d_in[1];
    float* out = (float*)d_out;
    (void)in_sizes; (void)n_in; (void)out_size; (void)d_ws; (void)ws_size;
    corr_mfma_kernel<<<dim3(2 * 4 * 128), dim3(256), 0, stream>>>(left, right, out);
}

// Round 3
// 149.122 us; speedup vs baseline: 1.7724x; 1.7724x over previous
//
#include <hip/hip_runtime.h>
#include <hip/hip_bf16.h>
#include <stdint.h>

typedef __bf16 bf16x8 __attribute__((ext_vector_type(8)));
typedef float f32x4 __attribute__((ext_vector_type(4)));

#define MAXD 40
#define ND   81
#define CSZ  256
#define HSZ  128
#define WSZ  416
#define HW   (HSZ * WSZ)
#define RST  40          // bf16 per LDS row: 32 data + 8 pad (80 B)
#define NCHUNK 8

__global__ __launch_bounds__(512, 2)
void corr_mfma_kernel(const float* __restrict__ left,
                      const float* __restrict__ right,
                      float* __restrict__ out) {
    __shared__ __align__(16) __bf16 Lt[WSZ * RST];   // [w][c]      33280 B
    __shared__ __align__(16) __bf16 Rt[512 * RST];   // [u+48][c]   40960 B

    const int t   = threadIdx.x;
    const int wv  = t >> 6;      // 0..7
    const int l   = t & 63;
    const int l15 = l & 15;
    const int l4  = l >> 4;      // 0..3
    const int b   = blockIdx.x >> 7;
    const int h   = blockIdx.x & 127;

    // staging coords: lane15 -> channel (16/ wave-half), l4 -> w-quad -> coalesced 64B runs
    const int sc = 16 * (wv & 1) + l15;   // channel-in-chunk 0..31
    const int sq = 4 * (wv >> 1) + l4;    // quad-in-16-group 0..15

    const size_t slab = ((size_t)b * CSZ) * HW + (size_t)h * WSZ;
    const float* Lp = left  + slab + (size_t)sc * HW;
    const float* Rp = right + slab + (size_t)sc * HW;

    f32x4 acc[4][6];
    #pragma unroll
    for (int ri = 0; ri < 4; ++ri)
        #pragma unroll
        for (int j = 0; j < 6; ++j)
            acc[ri][j] = (f32x4)0.0f;

    for (int ck = 0; ck < NCHUNK; ++ck) {
        const size_t cof = (size_t)ck * 32 * HW;

        // ---- batched load phase: issue all 15 float4 loads before any LDS op ----
        float4 lv[7];
        #pragma unroll
        for (int i = 0; i < 7; ++i) {
            const int q = 16 * i + sq;            // 0..111 (L has 104 quads)
            if (q < 104) lv[i] = *(const float4*)(Lp + cof + 4 * q);
            else         lv[i] = make_float4(0.f, 0.f, 0.f, 0.f);
        }
        float4 rv[8];
        #pragma unroll
        for (int i = 0; i < 8; ++i) {
            const int q = 16 * i + sq;            // 0..127 -> u0 = 4q-48
            if ((unsigned)(q - 12) < 104u) rv[i] = *(const float4*)(Rp + cof + (4 * q - 48));
            else                           rv[i] = make_float4(0.f, 0.f, 0.f, 0.f);
        }

        __syncthreads();   // previous MFMA done reading LDS

        // ---- cvt + LDS write (compiler interleaves partial vmcnt waits) ----
        #pragma unroll
        for (int i = 0; i < 7; ++i) {
            const int q = 16 * i + sq;
            if (q < 104) {
                #pragma unroll
                for (int k = 0; k < 4; ++k)
                    Lt[(4 * q + k) * RST + sc] = (__bf16)((&lv[i].x)[k]);
            }
        }
        #pragma unroll
        for (int i = 0; i < 8; ++i) {
            const int q = 16 * i + sq;
            #pragma unroll
            for (int k = 0; k < 4; ++k)
                Rt[(4 * q + k) * RST + sc] = (__bf16)((&rv[i].x)[k]);
        }

        __syncthreads();   // LDS tile ready

        // ---- banded MFMA: rows round-robin over 8 waves ----
        #pragma unroll
        for (int ri = 0; ri < 4; ++ri) {
            const int row = wv + 8 * ri;
            if (row < 26) {
                const bf16x8 a = *(const bf16x8*)&Lt[(16 * row + l15) * RST + 8 * l4];
                #pragma unroll
                for (int j = 0; j < 6; ++j) {
                    const bf16x8 bb = *(const bf16x8*)&Rt[(16 * (row + j) + 8 + l15) * RST + 8 * l4];
                    acc[ri][j] = __builtin_amdgcn_mfma_f32_16x16x32_bf16(a, bb, acc[ri][j], 0, 0, 0);
                }
            }
        }
        // next iteration's loads issue here (regs only) and overlap the barrier
    }

    // ---- epilogue: C row m=(l>>4)*4+r (w off), col n=l15 (u off); d = 16j + n - m ----
    const float scale = 1.0f / 256.0f;
    #pragma unroll
    for (int ri = 0; ri < 4; ++ri) {
        const int row = wv + 8 * ri;
        if (row < 26) {
            const int wbase = 16 * row;
            #pragma unroll
            for (int j = 0; j < 6; ++j) {
                #pragma unroll
                for (int r = 0; r < 4; ++r) {
                    const int m = 4 * l4 + r;
                    const int d = 16 * j + l15 - m;
                    if ((unsigned)d < (unsigned)ND) {
                        out[(((size_t)b * ND + d) * HSZ + h) * WSZ + (wbase + m)] = acc[ri][j][r] * scale;
                    }
                }
            }
        }
    }
}

extern "C" void kernel_launch(void* const* d_in, const int* in_sizes, int n_in,
                              void* d_out, int out_size, void* d_ws, size_t ws_size,
                              hipStream_t stream) {
    const float* left  = (const float*)d_in[0];
    const float* right = (const float*)d_in[1];
    float* out = (float*)d_out;
    (void)in_sizes; (void)n_in; (void)out_size; (void)d_ws; (void)ws_size;
    corr_mfma_kernel<<<dim3(4 * 128), dim3(512), 0, stream>>>(left, right, out);
}

// Round 4
// 145.107 us; speedup vs baseline: 1.8214x; 1.0277x over previous
//
#include <hip/hip_runtime.h>
#include <hip/hip_bf16.h>
#include <stdint.h>

typedef __bf16 bf16x8 __attribute__((ext_vector_type(8)));
typedef float f32x4 __attribute__((ext_vector_type(4)));

#define MAXD 40
#define ND   81
#define CSZ  256
#define HSZ  128
#define WSZ  416
#define HW   (HSZ * WSZ)
#define RST  40          // bf16 per LDS row: 32 data + 8 pad (80 B)
#define NCHUNK 8

// barrier with LDS-only drain: do NOT force vmcnt(0), so global loads
// issued before this barrier stay in flight across it (T4).
static __device__ __forceinline__ void lds_barrier() {
    asm volatile("s_waitcnt lgkmcnt(0)" ::: "memory");
    __builtin_amdgcn_s_barrier();
    __builtin_amdgcn_sched_barrier(0);
}

__global__ __launch_bounds__(512, 2)
void corr_mfma_kernel(const float* __restrict__ left,
                      const float* __restrict__ right,
                      float* __restrict__ out) {
    __shared__ __align__(16) __bf16 Lt[WSZ * RST];   // [w][c]      33280 B
    __shared__ __align__(16) __bf16 Rt[512 * RST];   // [u+48][c]   40960 B

    const int t   = threadIdx.x;
    const int wv  = t >> 6;      // 0..7
    const int l   = t & 63;
    const int l15 = l & 15;
    const int l4  = l >> 4;      // 0..3
    const int b   = blockIdx.x >> 7;
    const int h   = blockIdx.x & 127;

    // staging coords: l15 -> channel (16 per wave-half), sq -> w-quad (64B runs)
    const int sc = 16 * (wv & 1) + l15;   // channel-in-chunk 0..31
    const int sq = 4 * (wv >> 1) + l4;    // quad index 0..15

    const size_t slab = ((size_t)b * CSZ) * HW + (size_t)h * WSZ;
    const float* Lp = left  + slab + (size_t)sc * HW;
    const float* Rp = right + slab + (size_t)sc * HW;

    f32x4 acc[4][6];
    #pragma unroll
    for (int ri = 0; ri < 4; ++ri)
        #pragma unroll
        for (int j = 0; j < 6; ++j)
            acc[ri][j] = (f32x4)0.0f;

    // ---- prologue: stage chunk 0 ----
    {
        float4 lv0[7], rv0[8];
        #pragma unroll
        for (int i = 0; i < 7; ++i) {
            const int q = 16 * i + sq;
            lv0[i] = (q < 104) ? *(const float4*)(Lp + 4 * q) : make_float4(0.f, 0.f, 0.f, 0.f);
        }
        #pragma unroll
        for (int i = 0; i < 8; ++i) {
            const int q = 16 * i + sq;
            rv0[i] = ((unsigned)(q - 12) < 104u) ? *(const float4*)(Rp + 4 * q - 48)
                                                 : make_float4(0.f, 0.f, 0.f, 0.f);
        }
        #pragma unroll
        for (int i = 0; i < 7; ++i) {
            const int q = 16 * i + sq;
            if (q < 104) {
                #pragma unroll
                for (int k = 0; k < 4; ++k)
                    Lt[(4 * q + k) * RST + sc] = (__bf16)((&lv0[i].x)[k]);
            }
        }
        #pragma unroll
        for (int i = 0; i < 8; ++i) {
            const int q = 16 * i + sq;
            #pragma unroll
            for (int k = 0; k < 4; ++k)
                Rt[(4 * q + k) * RST + sc] = (__bf16)((&rv0[i].x)[k]);
        }
    }
    lds_barrier();   // tile 0 visible

    for (int ck = 0; ck < NCHUNK; ++ck) {
        const bool more = (ck + 1 < NCHUNK);

        // ---- A) issue next-chunk loads EARLY (regs only; in flight across MFMA+barriers) ----
        float4 lv[7], rv[8];
        if (more) {
            const size_t cof = (size_t)(ck + 1) * 32 * HW;
            const float* Lc = Lp + cof;
            const float* Rc = Rp + cof;
            #pragma unroll
            for (int i = 0; i < 7; ++i) {
                const int q = 16 * i + sq;
                lv[i] = (q < 104) ? *(const float4*)(Lc + 4 * q) : make_float4(0.f, 0.f, 0.f, 0.f);
            }
            #pragma unroll
            for (int i = 0; i < 8; ++i) {
                const int q = 16 * i + sq;
                rv[i] = ((unsigned)(q - 12) < 104u) ? *(const float4*)(Rc + 4 * q - 48)
                                                    : make_float4(0.f, 0.f, 0.f, 0.f);
            }
        }

        // ---- B) banded MFMA on current tile ----
        #pragma unroll
        for (int ri = 0; ri < 4; ++ri) {
            const int row = wv + 8 * ri;
            if (row < 26) {
                const bf16x8 a = *(const bf16x8*)&Lt[(16 * row + l15) * RST + 8 * l4];
                #pragma unroll
                for (int j = 0; j < 6; ++j) {
                    const bf16x8 bb = *(const bf16x8*)&Rt[(16 * (row + j) + 8 + l15) * RST + 8 * l4];
                    acc[ri][j] = __builtin_amdgcn_mfma_f32_16x16x32_bf16(a, bb, acc[ri][j], 0, 0, 0);
                }
            }
        }

        if (more) {
            lds_barrier();   // all waves done READING tile ck (lgkm only, loads stay in flight)

            // ---- C) cvt + write tile ck+1 (compiler inserts partial vmcnt waits per use) ----
            #pragma unroll
            for (int i = 0; i < 7; ++i) {
                const int q = 16 * i + sq;
                if (q < 104) {
                    #pragma unroll
                    for (int k = 0; k < 4; ++k)
                        Lt[(4 * q + k) * RST + sc] = (__bf16)((&lv[i].x)[k]);
                }
            }
            #pragma unroll
            for (int i = 0; i < 8; ++i) {
                const int q = 16 * i + sq;
                #pragma unroll
                for (int k = 0; k < 4; ++k)
                    Rt[(4 * q + k) * RST + sc] = (__bf16)((&rv[i].x)[k]);
            }

            lds_barrier();   // tile ck+1 visible
        }
    }

    // ---- epilogue: C row m=(l>>4)*4+r (w off), col n=l15 (u off); d = 16j + n - m ----
    const float scale = 1.0f / 256.0f;
    #pragma unroll
    for (int ri = 0; ri < 4; ++ri) {
        const int row = wv + 8 * ri;
        if (row < 26) {
            const int wbase = 16 * row;
            #pragma unroll
            for (int j = 0; j < 6; ++j) {
                #pragma unroll
                for (int r = 0; r < 4; ++r) {
                    const int m = 4 * l4 + r;
                    const int d = 16 * j + l15 - m;
                    if ((unsigned)d < (unsigned)ND) {
                        out[(((size_t)b * ND + d) * HSZ + h) * WSZ + (wbase + m)] = acc[ri][j][r] * scale;
                    }
                }
            }
        }
    }
}

extern "C" void kernel_launch(void* const* d_in, const int* in_sizes, int n_in,
                              void* d_out, int out_size, void* d_ws, size_t ws_size,
                              hipStream_t stream) {
    const float* left  = (const float*)d_in[0];
    const float* right = (const float*)d_in[1];
    float* out = (float*)d_out;
    (void)in_sizes; (void)n_in; (void)out_size; (void)d_ws; (void)ws_size;
    corr_mfma_kernel<<<dim3(4 * 128), dim3(512), 0, stream>>>(left, right, out);
}